// Round 6
// baseline (2233.866 us; speedup 1.0000x reference)
//
#include <hip/hip_runtime.h>

// DFPS: density-weighted Manhattan furthest point sampling.
// points:   [B, N, 3] f32   (B=4, N=8192 fixed by the problem)
// features: [B, C, N] f32   (unused)
// npoint:   int scalar (device, d_in[2])
// out:      [B, npoint] int32 indices

#define NPTS 8192
#define DENS_BLOCK 256
#define DENS_SPLIT 4
#define FPS_THREADS 1024
#define FPS_P 8   // FPS_THREADS * FPS_P == NPTS

typedef float v2f __attribute__((ext_vector_type(2)));

// ---------------- density ----------------
// j-coords are wave-uniform -> scalar loads, no LDS, no barriers.
// Each block covers N/DENS_SPLIT j's; partial counts go to separate planes.

__global__ void dfps_density_partial(const float* __restrict__ pts,
                                     float* __restrict__ pen4, int N) {
#pragma clang fp contract(off)
    const float R2 = (float)(0.4 * 0.4);  // matches JAX scalar promotion
    const int b = blockIdx.y;
    const int z = blockIdx.z;
    const int i = blockIdx.x * blockDim.x + threadIdx.x;
    const float* P = pts + (size_t)b * N * 3;

    const v2f px2 = {P[i * 3 + 0], P[i * 3 + 0]};
    const v2f py2 = {P[i * 3 + 1], P[i * 3 + 1]};
    const v2f pz2 = {P[i * 3 + 2], P[i * 3 + 2]};

    const int j0 = z * (N / DENS_SPLIT);
    const int j1 = j0 + (N / DENS_SPLIT);

    int cnt = 0;
#pragma unroll 4
    for (int j = j0; j < j1; j += 2) {
        // uniform addresses -> scalar loads
        v2f qx = {P[3 * j + 0], P[3 * j + 3]};
        v2f qy = {P[3 * j + 1], P[3 * j + 4]};
        v2f qz = {P[3 * j + 2], P[3 * j + 5]};
        v2f dx = px2 - qx;
        v2f dy = py2 - qy;
        v2f dz = pz2 - qz;
        v2f d2 = dx * dx;       // contract(off): numpy mul-then-add rounding
        d2 = d2 + dy * dy;
        d2 = d2 + dz * dz;
        cnt += (d2.x <= R2) ? 1 : 0;
        cnt += (d2.y <= R2) ? 1 : 0;
    }
    pen4[(size_t)(z * 4 + b) * N + i] = (float)cnt;  // exact small-int float
}

// ---------------- FPS ----------------

// u64 max across the 64-lane wave via DPP (VALU pipe, no LDS round-trips).
// Result valid in lane 63.
#define DPP_STEP(ctrl, rmask)                                                   \
    {                                                                           \
        unsigned int nlo = (unsigned int)__builtin_amdgcn_update_dpp(           \
            0, (int)klo, (ctrl), (rmask), 0xF, false);                          \
        unsigned int nhi = (unsigned int)__builtin_amdgcn_update_dpp(           \
            0, (int)khi, (ctrl), (rmask), 0xF, false);                          \
        unsigned long long o = ((unsigned long long)nhi << 32) | nlo;           \
        unsigned long long c = ((unsigned long long)khi << 32) | klo;           \
        if (o > c) { klo = nlo; khi = nhi; }                                    \
    }

__global__ void __launch_bounds__(FPS_THREADS, 1)
dfps_fps_kernel(const float* __restrict__ pts,
                const float* __restrict__ pen4,
                const int* __restrict__ npoint_p,
                int* __restrict__ out, int N) {
#pragma clang fp contract(off)
    const int b = blockIdx.x;
    const int tid = threadIdx.x;
    const int lane = tid & 63;
    const int npoint = *npoint_p;
    const float* Pb = pts + (size_t)b * N * 3;
    const int base = tid * FPS_P;

    // Coordinate table in LDS (float4) -> one b128 winner fetch.
    __shared__ float4 tab[NPTS];                 // 128 KiB
    // Triple-buffered block-winner slot (ds_max_u64); every conflicting
    // access pair is separated by at least one __syncthreads() (see R3).
    __shared__ unsigned long long slot[3];

    // Per-thread state in registers (8 points -> ~45 live VGPRs).
    float x[FPS_P], y[FPS_P], z[FPS_P], md[FPS_P], pw[FPS_P];
    unsigned int lo[FPS_P];  // key low words: N-1-idx (min-idx tiebreak)
#pragma unroll
    for (int k = 0; k < FPS_P; ++k) {
        int idx = base + k;
        x[k] = Pb[idx * 3 + 0];
        y[k] = Pb[idx * 3 + 1];
        z[k] = Pb[idx * 3 + 2];
        md[k] = 1e10f;
        // penalty = 1 / (sum of 4 exact-integer partial counts)
        float c01 = pen4[(size_t)(0 * 4 + b) * N + idx] +
                    pen4[(size_t)(1 * 4 + b) * N + idx];
        float c23 = pen4[(size_t)(2 * 4 + b) * N + idx] +
                    pen4[(size_t)(3 * 4 + b) * N + idx];
        pw[k] = 1.0f / (c01 + c23);
        lo[k] = (unsigned int)(N - 1 - idx);
        tab[idx] = make_float4(x[k], y[k], z[k], 0.f);
    }
    if (tid == 0) { slot[0] = 0ull; slot[2] = 0ull; }  // slot[1] zeroed in body 0
    __syncthreads();

    int cur = 0;
    float cx = Pb[0], cy = Pb[1], cz = Pb[2];

    for (int t = 0; t < npoint; ++t) {
        if (tid == 0) {
            out[(size_t)b * npoint + t] = cur;
            slot[(t + 1) % 3] = 0ull;  // safe: last read was before barrier t-1
        }

        // Distance update + u64 argmax keys; 4 independent chains for ILP.
        unsigned long long ck0 = 0ull, ck1 = 0ull, ck2 = 0ull, ck3 = 0ull;
#pragma unroll
        for (int k = 0; k < FPS_P; ++k) {
            // w=[1,1,2]; fmaf(2,|dz|,s) == s + 2*|dz| bitwise (2*|dz| exact)
            float d = fabsf(x[k] - cx) + fabsf(y[k] - cy);
            d = fmaf(2.0f, fabsf(z[k] - cz), d);
            float m = fminf(md[k], d);
            md[k] = m;
            float v = m * pw[k];  // v >= 0 -> float bits order == uint order
            unsigned long long key =
                ((unsigned long long)__float_as_uint(v) << 32) | lo[k];
            if ((k & 3) == 0)      { if (key > ck0) ck0 = key; }
            else if ((k & 3) == 1) { if (key > ck1) ck1 = key; }
            else if ((k & 3) == 2) { if (key > ck2) ck2 = key; }
            else                   { if (key > ck3) ck3 = key; }
        }
        unsigned long long ka = ck0 > ck1 ? ck0 : ck1;
        unsigned long long kb = ck2 > ck3 ? ck2 : ck3;
        unsigned long long best = ka > kb ? ka : kb;

        // Wave64 u64 max via DPP: row_shr 1/2/4/8, then row_bcast 15/31.
        unsigned int klo = (unsigned int)best;
        unsigned int khi = (unsigned int)(best >> 32);
        DPP_STEP(0x111, 0xF)  // row_shr:1
        DPP_STEP(0x112, 0xF)  // row_shr:2
        DPP_STEP(0x114, 0xF)  // row_shr:4
        DPP_STEP(0x118, 0xF)  // row_shr:8
        DPP_STEP(0x142, 0xA)  // row_bcast:15 -> rows 1,3
        DPP_STEP(0x143, 0xC)  // row_bcast:31 -> rows 2,3

        if (lane == 63) {
            unsigned long long wk = ((unsigned long long)khi << 32) | klo;
            atomicMax(&slot[t % 3], wk);  // ds_max_u64
        }
        __syncthreads();  // single barrier per iteration

        unsigned long long bk = slot[t % 3];
        cur = (N - 1) - (int)(unsigned int)(bk & 0xFFFFFFFFull);
        float4 c = tab[cur];  // uniform address -> LDS broadcast read
        cx = c.x;
        cy = c.y;
        cz = c.z;
    }
}

extern "C" void kernel_launch(void* const* d_in, const int* in_sizes, int n_in,
                              void* d_out, int out_size, void* d_ws, size_t ws_size,
                              hipStream_t stream) {
    const float* points  = (const float*)d_in[0];
    const int*   npoint  = (const int*)d_in[2];
    int* out = (int*)d_out;

    const int B = 4;
    const int N = in_sizes[0] / (B * 3);  // 8192
    float* pen4 = (float*)d_ws;           // DENS_SPLIT * B * N floats = 512 KiB

    dim3 dgrid(N / DENS_BLOCK, B, DENS_SPLIT);
    dfps_density_partial<<<dgrid, DENS_BLOCK, 0, stream>>>(points, pen4, N);

    dfps_fps_kernel<<<B, FPS_THREADS, 0, stream>>>(points, pen4, npoint, out, N);
}

// Round 7
// 2175.692 us; speedup vs baseline: 1.0267x; 1.0267x over previous
//
#include <hip/hip_runtime.h>

// DFPS: density-weighted Manhattan furthest point sampling.
// points:   [B, N, 3] f32   (B=4, N=8192 fixed by the problem)
// features: [B, C, N] f32   (unused)
// npoint:   int scalar (device, d_in[2])
// out:      [B, npoint] int32 indices
//
// Structure: (1) density (split-4, ushort partial counts, no atomics)
//            (2) Morton bucket sort -> perm (spatial locality for pruning)
//            (3) FPS, 512 thr x 16 pts, wave-level EXACT pruning:
//                skip a wave's md-update iff dist(center, wave bbox) >= max md
//                of the wave (provable no-op; bitwise identical result).

#define NPTS 8192
#define DENS_BLOCK 256
#define DENS_SPLIT 4
#define FPS_THREADS 512
#define FPS_P 16   // FPS_THREADS * FPS_P == NPTS

typedef float v2f __attribute__((ext_vector_type(2)));

// ---------------- density ----------------
// j-coords are wave-uniform -> scalar loads, no LDS, no barriers.

__global__ void dfps_density_partial(const float* __restrict__ pts,
                                     unsigned short* __restrict__ pen4, int N) {
#pragma clang fp contract(off)
    const float R2 = (float)(0.4 * 0.4);  // matches JAX scalar promotion
    const int b = blockIdx.y;
    const int z = blockIdx.z;
    const int i = blockIdx.x * blockDim.x + threadIdx.x;
    const float* P = pts + (size_t)b * N * 3;

    const v2f px2 = {P[i * 3 + 0], P[i * 3 + 0]};
    const v2f py2 = {P[i * 3 + 1], P[i * 3 + 1]};
    const v2f pz2 = {P[i * 3 + 2], P[i * 3 + 2]};

    const int j0 = z * (N / DENS_SPLIT);
    const int j1 = j0 + (N / DENS_SPLIT);

    int cnt = 0;
#pragma unroll 4
    for (int j = j0; j < j1; j += 2) {
        v2f qx = {P[3 * j + 0], P[3 * j + 3]};
        v2f qy = {P[3 * j + 1], P[3 * j + 4]};
        v2f qz = {P[3 * j + 2], P[3 * j + 5]};
        v2f dx = px2 - qx;
        v2f dy = py2 - qy;
        v2f dz = pz2 - qz;
        v2f d2 = dx * dx;       // contract(off): numpy mul-then-add rounding
        d2 = d2 + dy * dy;
        d2 = d2 + dz * dz;
        cnt += (d2.x <= R2) ? 1 : 0;
        cnt += (d2.y <= R2) ? 1 : 0;
    }
    pen4[(size_t)(z * 4 + b) * N + i] = (unsigned short)cnt;  // cnt <= 8192
}

// ---------------- Morton bucket sort (locality only; any perm is correct) ---

__device__ __forceinline__ unsigned spread10(unsigned x) {
    x &= 1023u;
    x = (x | (x << 16)) & 0x030000FFu;
    x = (x | (x << 8))  & 0x0300F00Fu;
    x = (x | (x << 4))  & 0x030C30C3u;
    x = (x | (x << 2))  & 0x09249249u;
    return x;
}

__global__ void __launch_bounds__(1024)
dfps_sort_kernel(const float* __restrict__ pts, int* __restrict__ perm, int N) {
    const int b = blockIdx.x;
    const int tid = threadIdx.x;
    const float* P = pts + (size_t)b * N * 3;
    const int PPT = N / 1024;  // 8

    __shared__ unsigned smin[3], smax[3];
    __shared__ unsigned bins[512];
    __shared__ unsigned offs[512];
    if (tid < 3) { smin[tid] = 0xFFFFFFFFu; smax[tid] = 0u; }
    if (tid < 512) bins[tid] = 0u;
    __syncthreads();

    // orderable-uint map for float min/max via integer atomics
    unsigned mn[3] = {0xFFFFFFFFu, 0xFFFFFFFFu, 0xFFFFFFFFu}, mx[3] = {0u, 0u, 0u};
    for (int k = 0; k < PPT; ++k) {
        int i = tid * PPT + k;
#pragma unroll
        for (int ax = 0; ax < 3; ++ax) {
            unsigned u = __float_as_uint(P[i * 3 + ax]);
            u = (u & 0x80000000u) ? ~u : (u | 0x80000000u);
            mn[ax] = min(mn[ax], u);
            mx[ax] = max(mx[ax], u);
        }
    }
#pragma unroll
    for (int ax = 0; ax < 3; ++ax) {
        atomicMin(&smin[ax], mn[ax]);
        atomicMax(&smax[ax], mx[ax]);
    }
    __syncthreads();

    float fmn[3], scale[3];
#pragma unroll
    for (int ax = 0; ax < 3; ++ax) {
        unsigned a = smin[ax], m = smax[ax];
        float fa = (a & 0x80000000u) ? __uint_as_float(a & 0x7FFFFFFFu)
                                     : __uint_as_float(~a);
        float fb = (m & 0x80000000u) ? __uint_as_float(m & 0x7FFFFFFFu)
                                     : __uint_as_float(~m);
        fmn[ax] = fa;
        scale[ax] = 1023.0f / fmaxf(fb - fa, 1e-20f);
    }

    unsigned mybin[8];
    for (int k = 0; k < PPT; ++k) {
        int i = tid * PPT + k;
        unsigned q[3];
#pragma unroll
        for (int ax = 0; ax < 3; ++ax) {
            int v = (int)((P[i * 3 + ax] - fmn[ax]) * scale[ax]);
            q[ax] = (unsigned)min(max(v, 0), 1023);
        }
        unsigned code = spread10(q[0]) | (spread10(q[1]) << 1) | (spread10(q[2]) << 2);
        mybin[k] = code >> 21;  // top 9 of 30 bits -> 512 buckets
        atomicAdd(&bins[mybin[k]], 1u);
    }
    __syncthreads();

    // exclusive scan over 512 bins (Hillis-Steele)
    unsigned own = (tid < 512) ? bins[tid] : 0u;
    if (tid < 512) offs[tid] = own;
    __syncthreads();
    for (int off = 1; off < 512; off <<= 1) {
        unsigned add = 0u;
        if (tid < 512 && tid >= off) add = offs[tid - off];
        __syncthreads();
        if (tid < 512) offs[tid] += add;
        __syncthreads();
    }
    if (tid < 512) offs[tid] -= own;  // exclusive
    __syncthreads();

    for (int k = 0; k < PPT; ++k) {
        int i = tid * PPT + k;
        unsigned pos = atomicAdd(&offs[mybin[k]], 1u);
        perm[(size_t)b * N + pos] = i;
    }
}

// ---------------- FPS ----------------

// u64 max across the 64-lane wave via DPP; result valid in lane 63.
#define DPP_STEP(ctrl, rmask)                                                   \
    {                                                                           \
        unsigned int nlo = (unsigned int)__builtin_amdgcn_update_dpp(           \
            0, (int)klo, (ctrl), (rmask), 0xF, false);                          \
        unsigned int nhi = (unsigned int)__builtin_amdgcn_update_dpp(           \
            0, (int)khi, (ctrl), (rmask), 0xF, false);                          \
        unsigned long long o = ((unsigned long long)nhi << 32) | nlo;           \
        unsigned long long c = ((unsigned long long)khi << 32) | klo;           \
        if (o > c) { klo = nlo; khi = nhi; }                                    \
    }

// f32 max across the wave via DPP (nonneg values; 0-passthrough safe).
#define DPP_MAXF(ctrl, rmask)                                                   \
    {                                                                           \
        float o_ = __uint_as_float((unsigned)__builtin_amdgcn_update_dpp(       \
            0, (int)__float_as_uint(mm), (ctrl), (rmask), 0xF, false));         \
        mm = fmaxf(mm, o_);                                                     \
    }

__global__ void __launch_bounds__(FPS_THREADS, 1)
dfps_fps_kernel(const float* __restrict__ pts,
                const unsigned short* __restrict__ pen4,
                const int* __restrict__ perm,
                const int* __restrict__ npoint_p,
                int* __restrict__ out, int N) {
#pragma clang fp contract(off)
    const int b = blockIdx.x;
    const int tid = threadIdx.x;
    const int lane = tid & 63;
    const int npoint = *npoint_p;
    const float* Pb = pts + (size_t)b * N * 3;
    const int* pb = perm + (size_t)b * N;
    const int base = tid * FPS_P;

    // Coordinate table in LDS, ORIGINAL index order -> winner lookup direct.
    __shared__ float4 tab[NPTS];                 // 128 KiB
    // Triple-buffered block-winner slot (ds_max_u64); every conflicting
    // access pair is separated by at least one __syncthreads() (see R3).
    __shared__ unsigned long long slot[3];

    // Per-thread state: 16 Morton-adjacent points (gathered via perm).
    float x[FPS_P], y[FPS_P], z[FPS_P], md[FPS_P], pw[FPS_P];
    unsigned int lo[FPS_P];  // key low words: N-1-ORIGINAL idx (tiebreak+output)
#pragma unroll
    for (int k = 0; k < FPS_P; ++k) {
        int p = pb[base + k];
        x[k] = Pb[p * 3 + 0];
        y[k] = Pb[p * 3 + 1];
        z[k] = Pb[p * 3 + 2];
        md[k] = 1e10f;
        int c01 = (int)pen4[(size_t)(0 * 4 + b) * N + p] +
                  (int)pen4[(size_t)(1 * 4 + b) * N + p];
        int c23 = (int)pen4[(size_t)(2 * 4 + b) * N + p] +
                  (int)pen4[(size_t)(3 * 4 + b) * N + p];
        pw[k] = 1.0f / (float)(c01 + c23);  // exact integer count
        lo[k] = (unsigned int)(N - 1 - p);
        tab[p] = make_float4(x[k], y[k], z[k], 0.f);
    }

    // Per-lane bbox over my 16 points, then wave bbox (butterfly -> all lanes).
    float blx = x[0], bhx = x[0], bly = y[0], bhy = y[0], blz = z[0], bhz = z[0];
#pragma unroll
    for (int k = 1; k < FPS_P; ++k) {
        blx = fminf(blx, x[k]); bhx = fmaxf(bhx, x[k]);
        bly = fminf(bly, y[k]); bhy = fmaxf(bhy, y[k]);
        blz = fminf(blz, z[k]); bhz = fmaxf(bhz, z[k]);
    }
    for (int off = 32; off > 0; off >>= 1) {
        blx = fminf(blx, __shfl_xor(blx, off));
        bhx = fmaxf(bhx, __shfl_xor(bhx, off));
        bly = fminf(bly, __shfl_xor(bly, off));
        bhy = fmaxf(bhy, __shfl_xor(bhy, off));
        blz = fminf(blz, __shfl_xor(blz, off));
        bhz = fmaxf(bhz, __shfl_xor(bhz, off));
    }

    if (tid == 0) { slot[0] = 0ull; slot[2] = 0ull; }  // slot[1] zeroed in body 0
    __syncthreads();

    int cur = 0;
    float cx = Pb[0], cy = Pb[1], cz = Pb[2];
    float wmdmax = 1e10f;          // max md over this wave (exact, refreshed on update)
    unsigned int klo = 0u, khi = 0u;  // cached wave-reduced winner key (lane 63)

    for (int t = 0; t < npoint; ++t) {
        if (tid == 0) {
            out[(size_t)b * npoint + t] = cur;
            slot[(t + 1) % 3] = 0ull;  // safe: last read was before barrier t-1
        }

        // Wave-level exact prune: weighted-Manhattan dist from center to wave
        // bbox. If lb >= wmdmax, min(md,d) is a no-op for every point in the
        // wave -> md, v, and the cached reduced key are all unchanged.
        float lbx = fmaxf(fmaxf(blx - cx, cx - bhx), 0.f);
        float lby = fmaxf(fmaxf(bly - cy, cy - bhy), 0.f);
        float lbz = fmaxf(fmaxf(blz - cz, cz - bhz), 0.f);
        float lb = (lbx + lby + 2.0f * lbz) * 0.99975f;  // >=5-ulp rounding guard
        int doupd = __builtin_amdgcn_readfirstlane((int)(lb < wmdmax));

        if (doupd) {
            // Distance update + u64 argmax keys; 4 independent chains for ILP.
            unsigned long long ck0 = 0ull, ck1 = 0ull, ck2 = 0ull, ck3 = 0ull;
#pragma unroll
            for (int k = 0; k < FPS_P; ++k) {
                // w=[1,1,2]; fmaf(2,|dz|,s) == s + 2*|dz| bitwise
                float d = fabsf(x[k] - cx) + fabsf(y[k] - cy);
                d = fmaf(2.0f, fabsf(z[k] - cz), d);
                float m = fminf(md[k], d);
                md[k] = m;
                float v = m * pw[k];  // v >= 0 -> float bit order == uint order
                unsigned long long key =
                    ((unsigned long long)__float_as_uint(v) << 32) | lo[k];
                if ((k & 3) == 0)      { if (key > ck0) ck0 = key; }
                else if ((k & 3) == 1) { if (key > ck1) ck1 = key; }
                else if ((k & 3) == 2) { if (key > ck2) ck2 = key; }
                else                   { if (key > ck3) ck3 = key; }
            }
            unsigned long long ka = ck0 > ck1 ? ck0 : ck1;
            unsigned long long kb = ck2 > ck3 ? ck2 : ck3;
            unsigned long long best = ka > kb ? ka : kb;

            klo = (unsigned int)best;
            khi = (unsigned int)(best >> 32);
            DPP_STEP(0x111, 0xF)  // row_shr:1
            DPP_STEP(0x112, 0xF)  // row_shr:2
            DPP_STEP(0x114, 0xF)  // row_shr:4
            DPP_STEP(0x118, 0xF)  // row_shr:8
            DPP_STEP(0x142, 0xA)  // row_bcast:15 -> rows 1,3
            DPP_STEP(0x143, 0xC)  // row_bcast:31 -> rows 2,3

            // Refresh wmdmax = max md over the wave.
            float mm = md[0];
#pragma unroll
            for (int k = 1; k < FPS_P; ++k) mm = fmaxf(mm, md[k]);
            DPP_MAXF(0x111, 0xF)
            DPP_MAXF(0x112, 0xF)
            DPP_MAXF(0x114, 0xF)
            DPP_MAXF(0x118, 0xF)
            DPP_MAXF(0x142, 0xA)
            DPP_MAXF(0x143, 0xC)
            wmdmax = __uint_as_float(
                (unsigned)__builtin_amdgcn_readlane((int)__float_as_uint(mm), 63));
        }

        if (lane == 63) {
            unsigned long long wk = ((unsigned long long)khi << 32) | klo;
            atomicMax(&slot[t % 3], wk);  // ds_max_u64
        }
        __syncthreads();  // single barrier per iteration

        unsigned long long bk = slot[t % 3];
        cur = (N - 1) - (int)(unsigned int)(bk & 0xFFFFFFFFull);  // ORIGINAL idx
        float4 c = tab[cur];  // uniform address -> LDS broadcast read
        cx = c.x;
        cy = c.y;
        cz = c.z;
    }
}

extern "C" void kernel_launch(void* const* d_in, const int* in_sizes, int n_in,
                              void* d_out, int out_size, void* d_ws, size_t ws_size,
                              hipStream_t stream) {
    const float* points  = (const float*)d_in[0];
    const int*   npoint  = (const int*)d_in[2];
    int* out = (int*)d_out;

    const int B = 4;
    const int N = in_sizes[0] / (B * 3);  // 8192

    // ws layout: pen4 (4*B*N ushort = 256 KiB) | perm (B*N int = 128 KiB)
    unsigned short* pen4 = (unsigned short*)d_ws;
    int* perm = (int*)((char*)d_ws + (size_t)DENS_SPLIT * B * N * sizeof(unsigned short));

    dim3 dgrid(N / DENS_BLOCK, B, DENS_SPLIT);
    dfps_density_partial<<<dgrid, DENS_BLOCK, 0, stream>>>(points, pen4, N);

    dfps_sort_kernel<<<B, 1024, 0, stream>>>(points, perm, N);

    dfps_fps_kernel<<<B, FPS_THREADS, 0, stream>>>(points, pen4, perm, npoint, out, N);
}

// Round 8
// 2091.930 us; speedup vs baseline: 1.0678x; 1.0400x over previous
//
#include <hip/hip_runtime.h>

// DFPS: density-weighted Manhattan furthest point sampling.
// points:   [B, N, 3] f32   (B=4, N=8192 fixed by the problem)
// features: [B, C, N] f32   (unused)
// npoint:   int scalar (device, d_in[2])
// out:      [B, npoint] int32 indices
//
// FPS key trick: key_f64 = (double)v  with (N-1-idx) OR'd into the low 13
// mantissa bits. f32->f64 is exact (29 zero low bits), so value ordering is
// unaffected and ties resolve to the smallest index. v >= 0 means the f64
// bit pattern is monotone as u64 -> DPP u64-max reduce + ds_max_u64 slot
// operate directly on the bits. One v_max_f64 per point replaces the whole
// (mov,mov,cmp_u64,cndmask,cndmask) chain.
// Also: v[k] = min(v[k], d*pw[k]) replaces min(md,d)*pw — bitwise identical
// (x -> rnd(x*pw) is monotone, so min commutes through it), saving md[].

#define NPTS 8192
#define DENS_BLOCK 256
#define DENS_SPLIT 4
#define FPS_THREADS 512
#define FPS_P 16   // FPS_THREADS * FPS_P == NPTS

typedef float v2f __attribute__((ext_vector_type(2)));

// ---------------- density ----------------
// j-coords are wave-uniform -> scalar loads, no LDS, no barriers.

__global__ void dfps_density_partial(const float* __restrict__ pts,
                                     unsigned short* __restrict__ pen4, int N) {
#pragma clang fp contract(off)
    const float R2 = (float)(0.4 * 0.4);  // matches JAX scalar promotion
    const int b = blockIdx.y;
    const int z = blockIdx.z;
    const int i = blockIdx.x * blockDim.x + threadIdx.x;
    const float* P = pts + (size_t)b * N * 3;

    const v2f px2 = {P[i * 3 + 0], P[i * 3 + 0]};
    const v2f py2 = {P[i * 3 + 1], P[i * 3 + 1]};
    const v2f pz2 = {P[i * 3 + 2], P[i * 3 + 2]};

    const int j0 = z * (N / DENS_SPLIT);
    const int j1 = j0 + (N / DENS_SPLIT);

    int cnt = 0;
#pragma unroll 4
    for (int j = j0; j < j1; j += 2) {
        v2f qx = {P[3 * j + 0], P[3 * j + 3]};
        v2f qy = {P[3 * j + 1], P[3 * j + 4]};
        v2f qz = {P[3 * j + 2], P[3 * j + 5]};
        v2f dx = px2 - qx;
        v2f dy = py2 - qy;
        v2f dz = pz2 - qz;
        v2f d2 = dx * dx;       // contract(off): numpy mul-then-add rounding
        d2 = d2 + dy * dy;
        d2 = d2 + dz * dz;
        cnt += (d2.x <= R2) ? 1 : 0;
        cnt += (d2.y <= R2) ? 1 : 0;
    }
    pen4[(size_t)(z * 4 + b) * N + i] = (unsigned short)cnt;  // cnt <= 8192
}

// ---------------- FPS ----------------

// u64 max across the 64-lane wave via DPP; result valid in lane 63.
#define DPP_STEP(ctrl, rmask)                                                   \
    {                                                                           \
        unsigned int nlo = (unsigned int)__builtin_amdgcn_update_dpp(           \
            0, (int)klo, (ctrl), (rmask), 0xF, false);                          \
        unsigned int nhi = (unsigned int)__builtin_amdgcn_update_dpp(           \
            0, (int)khi, (ctrl), (rmask), 0xF, false);                          \
        unsigned long long o = ((unsigned long long)nhi << 32) | nlo;           \
        unsigned long long c = ((unsigned long long)khi << 32) | klo;           \
        if (o > c) { klo = nlo; khi = nhi; }                                    \
    }

__global__ void __launch_bounds__(FPS_THREADS, 1)
dfps_fps_kernel(const float* __restrict__ pts,
                const unsigned short* __restrict__ pen4,
                const int* __restrict__ npoint_p,
                int* __restrict__ out, int N) {
#pragma clang fp contract(off)
    const int b = blockIdx.x;
    const int tid = threadIdx.x;
    const int lane = tid & 63;
    const int npoint = *npoint_p;
    const float* Pb = pts + (size_t)b * N * 3;
    const int base = tid * FPS_P;

    // Coordinate table in LDS (float4) -> one b128 winner fetch.
    __shared__ float4 tab[NPTS];                 // 128 KiB
    // Triple-buffered block-winner slot (ds_max_u64); every conflicting
    // access pair is separated by at least one __syncthreads() (see R3).
    __shared__ unsigned long long slot[3];

    // Per-thread state: coords, and v[k] = md[k]*pw[k] (md itself not kept).
    float x[FPS_P], y[FPS_P], z[FPS_P], pw[FPS_P], v[FPS_P];
#pragma unroll
    for (int k = 0; k < FPS_P; ++k) {
        int idx = base + k;
        x[k] = Pb[idx * 3 + 0];
        y[k] = Pb[idx * 3 + 1];
        z[k] = Pb[idx * 3 + 2];
        int c01 = (int)pen4[(size_t)(0 * 4 + b) * N + idx] +
                  (int)pen4[(size_t)(1 * 4 + b) * N + idx];
        int c23 = (int)pen4[(size_t)(2 * 4 + b) * N + idx] +
                  (int)pen4[(size_t)(3 * 4 + b) * N + idx];
        pw[k] = 1.0f / (float)(c01 + c23);  // exact integer count
        v[k] = 1e10f * pw[k];               // rnd(1e10*pw) == ref's t=0 value
        tab[idx] = make_float4(x[k], y[k], z[k], 0.f);
    }
    if (tid == 0) { slot[0] = 0ull; slot[2] = 0ull; }  // slot[1] zeroed in body 0
    __syncthreads();

    int cur = 0;
    float cx = Pb[0], cy = Pb[1], cz = Pb[2];

    for (int t = 0; t < npoint; ++t) {
        if (tid == 0) {
            out[(size_t)b * npoint + t] = cur;
            slot[(t + 1) % 3] = 0ull;  // safe: last read was before barrier t-1
        }

        // Distance update + f64-packed argmax keys; 4 chains for ILP.
        double m0 = 0.0, m1 = 0.0, m2 = 0.0, m3 = 0.0;
#pragma unroll
        for (int k = 0; k < FPS_P; ++k) {
            // w=[1,1,2]; fmaf(2,|dz|,s) == s + 2*|dz| bitwise (2*|dz| exact)
            float d = fabsf(x[k] - cx) + fabsf(y[k] - cy);
            d = fmaf(2.0f, fabsf(z[k] - cz), d);
            // v[k] = min over iters of rnd(d*pw) == rnd(min(md,d)*pw): monotone
            float nv = fminf(v[k], d * pw[k]);
            v[k] = nv;
            // f64 key: exact f32->f64 cvt, index field in low 13 mantissa bits
            unsigned long long kb = __double_as_longlong((double)nv) |
                                    (unsigned long long)(unsigned)(N - 1 - (base + k));
            double kd = __longlong_as_double(kb);
            if ((k & 3) == 0)      m0 = fmax(m0, kd);
            else if ((k & 3) == 1) m1 = fmax(m1, kd);
            else if ((k & 3) == 2) m2 = fmax(m2, kd);
            else                   m3 = fmax(m3, kd);
        }
        double ma = fmax(m0, m1);
        double mb = fmax(m2, m3);
        unsigned long long best = __double_as_longlong(fmax(ma, mb));

        // Wave64 u64 max via DPP (nonneg f64 bits are u64-monotone).
        unsigned int klo = (unsigned int)best;
        unsigned int khi = (unsigned int)(best >> 32);
        DPP_STEP(0x111, 0xF)  // row_shr:1
        DPP_STEP(0x112, 0xF)  // row_shr:2
        DPP_STEP(0x114, 0xF)  // row_shr:4
        DPP_STEP(0x118, 0xF)  // row_shr:8
        DPP_STEP(0x142, 0xA)  // row_bcast:15 -> rows 1,3
        DPP_STEP(0x143, 0xC)  // row_bcast:31 -> rows 2,3

        if (lane == 63) {
            unsigned long long wk = ((unsigned long long)khi << 32) | klo;
            atomicMax(&slot[t % 3], wk);  // ds_max_u64 (== f64 max, nonneg)
        }
        __syncthreads();  // single barrier per iteration

        unsigned long long bk = slot[t % 3];
        // index field: bits [0,13) of the low word (bits [13,29) are zero)
        cur = (N - 1) - (int)((unsigned int)bk & (unsigned int)(N - 1));
        float4 c = tab[cur];  // uniform address -> LDS broadcast read
        cx = c.x;
        cy = c.y;
        cz = c.z;
    }
}

extern "C" void kernel_launch(void* const* d_in, const int* in_sizes, int n_in,
                              void* d_out, int out_size, void* d_ws, size_t ws_size,
                              hipStream_t stream) {
    const float* points  = (const float*)d_in[0];
    const int*   npoint  = (const int*)d_in[2];
    int* out = (int*)d_out;

    const int B = 4;
    const int N = in_sizes[0] / (B * 3);  // 8192
    unsigned short* pen4 = (unsigned short*)d_ws;  // 4*B*N ushort = 256 KiB

    dim3 dgrid(N / DENS_BLOCK, B, DENS_SPLIT);
    dfps_density_partial<<<dgrid, DENS_BLOCK, 0, stream>>>(points, pen4, N);

    dfps_fps_kernel<<<B, FPS_THREADS, 0, stream>>>(points, pen4, npoint, out, N);
}

// Round 9
// 1933.482 us; speedup vs baseline: 1.1554x; 1.0819x over previous
//
#include <hip/hip_runtime.h>

// DFPS: density-weighted Manhattan furthest point sampling.
// points:   [B, N, 3] f32   (B=4, N=8192 fixed by the problem)
// features: [B, C, N] f32   (unused)
// npoint:   int scalar (device, d_in[2])
// out:      [B, npoint] int32 indices
//
// FPS structure (R8): f32-only argmax payload, lazy index resolution.
//  phase 1: nv = fmin(v, d*pw) per point + f32 chain max (8 VALU/pt),
//           wave DPP f32-max, lane63 ds_max_u32 (f32 bits monotone, v>=0).
//  barrier A; read block max bm.
//  phase 2: waves owning bm (thread-max == bm) scan their 16 values for
//           equality and atomicMin the ORIGINAL index -> first-occurrence
//           tie semantics, bit-exact vs reference (v is bitwise identical
//           to ref's min(md,d)*pw by monotonicity of x->rnd(x*pw)).
//  barrier B; read index slot, fetch coords from LDS float4 table.

#define NPTS 8192
#define DENS_BLOCK 256
#define DENS_SPLIT 4
#define FPS_THREADS 512
#define FPS_P 16   // FPS_THREADS * FPS_P == NPTS

typedef float v2f __attribute__((ext_vector_type(2)));

// ---------------- density ----------------
// j-coords are wave-uniform -> scalar loads, no LDS, no barriers.

__global__ void dfps_density_partial(const float* __restrict__ pts,
                                     unsigned short* __restrict__ pen4, int N) {
#pragma clang fp contract(off)
    const float R2 = (float)(0.4 * 0.4);  // matches JAX scalar promotion
    const int b = blockIdx.y;
    const int z = blockIdx.z;
    const int i = blockIdx.x * blockDim.x + threadIdx.x;
    const float* P = pts + (size_t)b * N * 3;

    const v2f px2 = {P[i * 3 + 0], P[i * 3 + 0]};
    const v2f py2 = {P[i * 3 + 1], P[i * 3 + 1]};
    const v2f pz2 = {P[i * 3 + 2], P[i * 3 + 2]};

    const int j0 = z * (N / DENS_SPLIT);
    const int j1 = j0 + (N / DENS_SPLIT);

    int cnt = 0;
#pragma unroll 4
    for (int j = j0; j < j1; j += 2) {
        v2f qx = {P[3 * j + 0], P[3 * j + 3]};
        v2f qy = {P[3 * j + 1], P[3 * j + 4]};
        v2f qz = {P[3 * j + 2], P[3 * j + 5]};
        v2f dx = px2 - qx;
        v2f dy = py2 - qy;
        v2f dz = pz2 - qz;
        v2f d2 = dx * dx;       // contract(off): numpy mul-then-add rounding
        d2 = d2 + dy * dy;
        d2 = d2 + dz * dz;
        cnt += (d2.x <= R2) ? 1 : 0;
        cnt += (d2.y <= R2) ? 1 : 0;
    }
    pen4[(size_t)(z * 4 + b) * N + i] = (unsigned short)cnt;  // cnt <= 8192
}

// ---------------- FPS ----------------

// f32 max across the wave via DPP (nonneg values; 0-passthrough safe).
#define DPP_MAXF(ctrl, rmask)                                                   \
    {                                                                           \
        float o_ = __uint_as_float((unsigned)__builtin_amdgcn_update_dpp(       \
            0, (int)__float_as_uint(mm), (ctrl), (rmask), 0xF, false));         \
        mm = fmaxf(mm, o_);                                                     \
    }

__global__ void __launch_bounds__(FPS_THREADS, 1)
dfps_fps_kernel(const float* __restrict__ pts,
                const unsigned short* __restrict__ pen4,
                const int* __restrict__ npoint_p,
                int* __restrict__ out, int N) {
#pragma clang fp contract(off)
    const int b = blockIdx.x;
    const int tid = threadIdx.x;
    const int lane = tid & 63;
    const int npoint = *npoint_p;
    const float* Pb = pts + (size_t)b * N * 3;
    const int base = tid * FPS_P;

    // Coordinate table in LDS (float4) -> one b128 winner fetch.
    __shared__ float4 tab[NPTS];                 // 128 KiB
    // Triple-buffered (value, index) slots. Every conflicting access pair is
    // separated by >=1 barrier: atomicMax(v) pre-A, read(v) post-A,
    // atomicMin(i) pre-B, read(i) post-B, re-init 2 iters after last read.
    __shared__ unsigned int vslot[3];
    __shared__ unsigned int islot[3];

    // Per-thread state: coords, penalty, v[k] = running min of rnd(d*pw).
    float x[FPS_P], y[FPS_P], z[FPS_P], pw[FPS_P], v[FPS_P];
#pragma unroll
    for (int k = 0; k < FPS_P; ++k) {
        int idx = base + k;
        x[k] = Pb[idx * 3 + 0];
        y[k] = Pb[idx * 3 + 1];
        z[k] = Pb[idx * 3 + 2];
        int c01 = (int)pen4[(size_t)(0 * 4 + b) * N + idx] +
                  (int)pen4[(size_t)(1 * 4 + b) * N + idx];
        int c23 = (int)pen4[(size_t)(2 * 4 + b) * N + idx] +
                  (int)pen4[(size_t)(3 * 4 + b) * N + idx];
        pw[k] = 1.0f / (float)(c01 + c23);  // exact integer count
        v[k] = 1e10f * pw[k];               // rnd(1e10*pw) == ref's t=0 value
        tab[idx] = make_float4(x[k], y[k], z[k], 0.f);
    }
    if (tid == 0) {
        vslot[0] = 0u; islot[0] = 0xFFFFFFFFu;
        vslot[2] = 0u; islot[2] = 0xFFFFFFFFu;  // slot1 inited in body t=0
    }
    __syncthreads();

    int cur = 0;
    float cx = Pb[0], cy = Pb[1], cz = Pb[2];

    for (int t = 0; t < npoint; ++t) {
        if (tid == 0) {
            out[(size_t)b * npoint + t] = cur;
            vslot[(t + 1) % 3] = 0u;            // next iter's slots; last read
            islot[(t + 1) % 3] = 0xFFFFFFFFu;   // was 2 iters (4 barriers) ago
        }

        // Phase 1: distance update + f32 chain max (4 chains for ILP).
        float m0 = 0.f, m1 = 0.f, m2 = 0.f, m3 = 0.f;
#pragma unroll
        for (int k = 0; k < FPS_P; ++k) {
            // w=[1,1,2]; fmaf(2,|dz|,s) == s + 2*|dz| bitwise (2*|dz| exact)
            float d = fabsf(x[k] - cx) + fabsf(y[k] - cy);
            d = fmaf(2.0f, fabsf(z[k] - cz), d);
            // v[k] = min over iters of rnd(d*pw) == rnd(min(md,d)*pw) (monotone)
            float nv = fminf(v[k], d * pw[k]);
            v[k] = nv;
            if ((k & 3) == 0)      m0 = fmaxf(m0, nv);
            else if ((k & 3) == 1) m1 = fmaxf(m1, nv);
            else if ((k & 3) == 2) m2 = fmaxf(m2, nv);
            else                   m3 = fmaxf(m3, nv);
        }
        const float tb = fmaxf(fmaxf(m0, m1), fmaxf(m2, m3));  // thread max

        // Wave f32 max via DPP: row_shr 1/2/4/8, then row_bcast 15/31.
        float mm = tb;
        DPP_MAXF(0x111, 0xF)  // row_shr:1
        DPP_MAXF(0x112, 0xF)  // row_shr:2
        DPP_MAXF(0x114, 0xF)  // row_shr:4
        DPP_MAXF(0x118, 0xF)  // row_shr:8
        DPP_MAXF(0x142, 0xA)  // row_bcast:15 -> rows 1,3
        DPP_MAXF(0x143, 0xC)  // row_bcast:31 -> rows 2,3
        if (lane == 63)
            atomicMax(&vslot[t % 3], __float_as_uint(mm));  // ds_max_u32

        __syncthreads();  // barrier A: block max ready

        const float bm = __uint_as_float(vslot[t % 3]);

        // Phase 2: only threads whose max equals bm own a candidate; whole
        // waves with no owner skip via exec-mask branch (s_cbranch_execz).
        if (tb == bm) {
            unsigned cand = 0xFFFFFFFFu;
#pragma unroll
            for (int k = 0; k < FPS_P; ++k)
                if (v[k] == bm) cand = min(cand, (unsigned)(base + k));
            atomicMin(&islot[t % 3], cand);  // min ORIGINAL idx -> ref ties
        }

        __syncthreads();  // barrier B: index ready

        cur = (int)islot[t % 3];
        float4 c = tab[cur];  // uniform address -> LDS broadcast read
        cx = c.x;
        cy = c.y;
        cz = c.z;
    }
}

extern "C" void kernel_launch(void* const* d_in, const int* in_sizes, int n_in,
                              void* d_out, int out_size, void* d_ws, size_t ws_size,
                              hipStream_t stream) {
    const float* points  = (const float*)d_in[0];
    const int*   npoint  = (const int*)d_in[2];
    int* out = (int*)d_out;

    const int B = 4;
    const int N = in_sizes[0] / (B * 3);  // 8192
    unsigned short* pen4 = (unsigned short*)d_ws;  // 4*B*N ushort = 256 KiB

    dim3 dgrid(N / DENS_BLOCK, B, DENS_SPLIT);
    dfps_density_partial<<<dgrid, DENS_BLOCK, 0, stream>>>(points, pen4, N);

    dfps_fps_kernel<<<B, FPS_THREADS, 0, stream>>>(points, pen4, npoint, out, N);
}